// Round 4
// baseline (25.209 us; speedup 1.0000x reference)
//
#include <hip/hip_runtime.h>

// LPG: B=8, Hc=88, Wc=288, k=4 -> out (8, 9, 352, 1152) fp32 (~116.8 MB).
// out[b,p,h,w] = n3 / (n0*(u - hs) + n1*(v - ws) + n2)
//   hs = 4*(p/3 - 1), ws = 4*(p%3 - 1)
//   n_c = pe[b, c, clip(h/4 + p/3-1, 0, Hc-1), clip(w/4 + p%3-1, 0, Wc-1)]
//   u = ((w%4) - 1.5)/4, v = ((h%4) - 1.5)/4   (phases from UNclipped h,w)
//
// One thread owns a 4x4 output block (fixed p,hb,wb) for FOUR batches
// (b0, b0+2, b0+4, b0+6): identical p/row/col/clamps/phases, only the coef
// pointer (+2*4*HcWc) and output plane (+18 planes) change. All 16 coef
// loads are issued before any compute (single vmcnt drain), then 16 nt
// float4 stores. grid=(99,18): 1782 blocks ~= 7/CU, single resident round.
// n3/den via v_rcp_f32 (~1 ulp); absmax threshold 60.8, measured 0.0156.

constexpr int Hc    = 88;
constexpr int Wc    = 288;
constexpr int H     = Hc * 4;          // 352
constexpr int W4    = Wc;              // W/4 = 288 float4 per output row
constexpr int HcWc  = Hc * Wc;         // 25344
constexpr int PL4   = H * W4;          // 101376 float4 per output plane

typedef float f32x4 __attribute__((ext_vector_type(4)));

__global__ __launch_bounds__(256)
void lpg_kernel(const float* __restrict__ pe, float* __restrict__ out)
{
    int t  = blockIdx.x * 256 + threadIdx.x;   // [0, 25344) tile within plane
    int qy = blockIdx.y;                       // b0*9 + p, b0 in [0,2)

    int hb = t / 288;                          // single magic-mul chain
    int wb = t - hb * 288;

    int p   = qy % 9;                          // wave-uniform (scalar)
    int b0  = qy / 9;
    int pd3 = p / 3;
    int ihs = pd3 - 1;                         // -1, 0, 1
    int iws = p - 3 * pd3 - 1;                 // -1, 0, 1

    int row = min(max(hb + ihs, 0), Hc - 1);
    int col = min(max(wb + iws, 0), Wc - 1);

    float hs = (float)(4 * ihs);
    float ws = (float)(4 * iws);
    float u0 = -0.375f - hs;                   // u_j - hs = u0 + 0.25*j
    float v0 = -0.375f - ws;                   // v_r - ws = v0 + 0.25*r

    const float* bp = pe + (size_t)b0 * (4 * HcWc) + (size_t)row * Wc + col;

    // Hoist all 16 coefficient loads (4 batches x 4 channels) for max MLP.
    float n0[4], n1[4], n2[4], n3[4];
    #pragma unroll
    for (int k = 0; k < 4; ++k) {              // b = b0 + 2k
        const float* bk = bp + (size_t)k * (8 * HcWc);
        n0[k] = bk[0 * HcWc];
        n1[k] = bk[1 * HcWc];
        n2[k] = bk[2 * HcWc];
        n3[k] = bk[3 * HcWc];
    }

    f32x4* o4 = reinterpret_cast<f32x4*>(out)
              + (size_t)qy * PL4 + (size_t)(4 * hb) * W4 + wb;

    #pragma unroll
    for (int k = 0; k < 4; ++k) {
        float tu0 = n0[k] * u0;
        float tu1 = n0[k] * (u0 + 0.25f);
        float tu2 = n0[k] * (u0 + 0.50f);
        float tu3 = n0[k] * (u0 + 0.75f);

        #pragma unroll
        for (int r = 0; r < 4; ++r) {
            float a = fmaf(n1[k], v0 + 0.25f * (float)r, n2[k]);
            f32x4 o;
            o.x = n3[k] * __builtin_amdgcn_rcpf(a + tu0);
            o.y = n3[k] * __builtin_amdgcn_rcpf(a + tu1);
            o.z = n3[k] * __builtin_amdgcn_rcpf(a + tu2);
            o.w = n3[k] * __builtin_amdgcn_rcpf(a + tu3);
            __builtin_nontemporal_store(o, o4 + (size_t)r * W4);
        }
        o4 += (size_t)18 * PL4;                // b += 2 -> +18 output planes
    }
}

extern "C" void kernel_launch(void* const* d_in, const int* in_sizes, int n_in,
                              void* d_out, int out_size, void* d_ws, size_t ws_size,
                              hipStream_t stream)
{
    const float* pe  = (const float*)d_in[0];
    float*       out = (float*)d_out;

    dim3 block(256);
    dim3 grid(HcWc / 256 /* 99 */, 18);        // 18 = 2 batch-groups * 9 planes
    lpg_kernel<<<grid, block, 0, stream>>>(pe, out);
}